// Round 7
// baseline (98.066 us; speedup 1.0000x reference)
//
#include <hip/hip_runtime.h>
#include <hip/hip_bf16.h>

#define N 1024
#define NBLK 256

typedef __attribute__((ext_vector_type(4))) short short4v;
typedef __attribute__((ext_vector_type(8))) short short8;
typedef __attribute__((ext_vector_type(4))) float f32x4;
typedef __attribute__((ext_vector_type(8))) float f32x8;

static __device__ __forceinline__ ushort bfbits(float f) {
    union { __hip_bfloat16 h; ushort u; } cv; cv.h = __float2bfloat16(f); return cv.u;
}
static __device__ __forceinline__ float bf2f(ushort u) {
    union { ushort u; __hip_bfloat16 h; } cv; cv.u = u; return __bfloat162float(cv.h);
}

#define MFMA16(a, b, c) __builtin_amdgcn_mfma_f32_16x16x32_bf16(a, b, c, 0, 0, 0)

// ---------------------------------------------------------------------------
// Single fused persistent kernel. 256 blocks x 512 threads = 1 block/CU
// (co-resident; __launch_bounds__(512,2) caps VGPR<=256 to guarantee it).
//   Phase A: Ph/Pl = bf16 hi/lo split of exp(W); psum[16][1024] slab sums.
//   [grid barrier]  Phase B: blocks 0-15 compute lcs[j] = log(colsum_j).
//   [grid barrier]  Phase C: out[m][i] = log(sum_j exp(la-lcs)*P), split-3
//   bf16 MFMA, K-split-8 (wave owns K=128 -> each Q/P element touched by
//   exactly ONE wave: direct global fragment loads, no LDS staging, no
//   intra-C barriers, Q computed inline so it never hits memory).
// All register arrays statically indexed via full unroll (rule #20: R6's
// regression was runtime-indexed prefetch arrays -> scratch).
// ---------------------------------------------------------------------------
__global__ __launch_bounds__(512, 2) void fused(const float* __restrict__ la,
                                                const float* __restrict__ W,
                                                float* __restrict__ out,
                                                unsigned* __restrict__ bar,
                                                float* __restrict__ lcs_g,
                                                float* __restrict__ psum,
                                                ushort* __restrict__ Ph,
                                                ushort* __restrict__ Pl) {
    __shared__ __align__(16) char smem_raw[8 * 64 * 4 * 16];   // 32 KB
    const int t = threadIdx.x;
    const int b = blockIdx.x;

    // ---------------- Phase A ----------------
    {
        const int cg = b & 15, slab = b >> 4;          // 16 col-grps x 16 slabs
        const int c4 = cg * 64 + (t & 15) * 4;
        f32x4* smA = (f32x4*)smem_raw;                 // [32][16]
        f32x4 part = {0.f, 0.f, 0.f, 0.f};
#pragma unroll
        for (int rr = 0; rr < 2; ++rr) {
            const int row = slab * 64 + rr * 32 + (t >> 4);
            const f32x4 v = *(const f32x4*)(W + row * N + c4);
            short4v ph, pl;
#pragma unroll
            for (int x = 0; x < 4; ++x) {
                const float e = __expf(v[x]);
                const ushort h = bfbits(e);
                ph[x] = (short)h;
                pl[x] = (short)bfbits(e - bf2f(h));
                part[x] += e;
            }
            *(short4v*)(Ph + row * N + c4) = ph;
            *(short4v*)(Pl + row * N + c4) = pl;
        }
        smA[(t >> 4) * 16 + (t & 15)] = part;
        __syncthreads();
        if (t < 16) {
            f32x4 s = smA[t];
#pragma unroll
            for (int g = 1; g < 32; ++g) s += smA[g * 16 + t];
            *(f32x4*)(psum + slab * N + cg * 64 + t * 4) = s;
        }
    }

    // ---------------- grid barrier 1 ----------------
    __syncthreads();
    if (t == 0) {
        __threadfence();
        atomicAdd(&bar[0], 1u);
        while (atomicAdd(&bar[0], 0u) < NBLK) __builtin_amdgcn_s_sleep(8);
        __threadfence();
    }
    __syncthreads();

    // ---------------- Phase B ----------------
    if (b < 16 && t < 64) {
        const int c = b * 64 + t;
        float s = 0.f;
#pragma unroll
        for (int sl = 0; sl < 16; ++sl) s += psum[sl * N + c];
        lcs_g[c] = __logf(s);
    }

    // ---------------- grid barrier 2 ----------------
    __syncthreads();
    if (t == 0) {
        __threadfence();
        atomicAdd(&bar[1], 1u);
        while (atomicAdd(&bar[1], 0u) < NBLK) __builtin_amdgcn_s_sleep(8);
        __threadfence();
    }
    __syncthreads();

    // ---------------- Phase C ----------------
    const int lane = t & 63, wid = t >> 6;
    const int fr = lane & 15, q = lane >> 4;
    const int m0 = (b >> 5) * 32, i0 = (b & 31) * 32;
    const int kc = wid * 128;                          // wave's K chunk

    const float*  plA0 = la + (m0 + fr) * N;
    const float*  plA1 = la + (m0 + 16 + fr) * N;
    const ushort* pB0h = Ph + (i0 + fr) * N;
    const ushort* pB1h = Ph + (i0 + 16 + fr) * N;
    const ushort* pB0l = Pl + (i0 + fr) * N;
    const ushort* pB1l = Pl + (i0 + 16 + fr) * N;

    f32x4 a00 = {0.f,0.f,0.f,0.f}, a01 = {0.f,0.f,0.f,0.f};
    f32x4 a10 = {0.f,0.f,0.f,0.f}, a11 = {0.f,0.f,0.f,0.f};

#pragma unroll
    for (int s = 0; s < 4; ++s) {                      // 4 k-slices of 32
        const int kk = kc + s * 32 + q * 8;
        const f32x8 v0   = *(const f32x8*)(plA0 + kk);
        const f32x8 v1   = *(const f32x8*)(plA1 + kk);
        const f32x8 vlc  = *(const f32x8*)(lcs_g + kk);
        const short8 b0h = *(const short8*)(pB0h + kk);
        const short8 b1h = *(const short8*)(pB1h + kk);
        const short8 b0l = *(const short8*)(pB0l + kk);
        const short8 b1l = *(const short8*)(pB1l + kk);
        short8 a0h, a0l, a1h, a1l;
#pragma unroll
        for (int x = 0; x < 8; ++x) {
            const float q0 = __expf(v0[x] - vlc[x]);
            const ushort h0 = bfbits(q0);
            a0h[x] = (short)h0;
            a0l[x] = (short)bfbits(q0 - bf2f(h0));
            const float q1 = __expf(v1[x] - vlc[x]);
            const ushort h1 = bfbits(q1);
            a1h[x] = (short)h1;
            a1l[x] = (short)bfbits(q1 - bf2f(h1));
        }
        a00 = MFMA16(a0h, b0h, a00); a00 = MFMA16(a0h, b0l, a00); a00 = MFMA16(a0l, b0h, a00);
        a01 = MFMA16(a0h, b1h, a01); a01 = MFMA16(a0h, b1l, a01); a01 = MFMA16(a0l, b1h, a01);
        a10 = MFMA16(a1h, b0h, a10); a10 = MFMA16(a1h, b0l, a10); a10 = MFMA16(a1l, b0h, a10);
        a11 = MFMA16(a1h, b1h, a11); a11 = MFMA16(a1h, b1l, a11); a11 = MFMA16(a1l, b1h, a11);
    }

    // K-split-8 reduce (reuse smem as [8][64][4] f32x4 = 32KB), then log+store
    __syncthreads();
    f32x4* red = (f32x4*)smem_raw;
    red[(wid * 64 + lane) * 4 + 0] = a00;
    red[(wid * 64 + lane) * 4 + 1] = a01;
    red[(wid * 64 + lane) * 4 + 2] = a10;
    red[(wid * 64 + lane) * 4 + 3] = a11;
    __syncthreads();
    if (wid < 4) {                   // wid picks output sub-tile (msub,nsub)
        f32x4 s = red[lane * 4 + wid];
#pragma unroll
        for (int w2 = 1; w2 < 8; ++w2) s += red[(w2 * 64 + lane) * 4 + wid];
        const int om = m0 + (wid >> 1) * 16 + q * 4;
        const int oi = i0 + (wid & 1) * 16 + fr;
#pragma unroll
        for (int r = 0; r < 4; ++r)
            out[(om + r) * N + oi] = __logf(s[r]);
    }
}

// ---------------------------------------------------------------------------
extern "C" void kernel_launch(void* const* d_in, const int* in_sizes, int n_in,
                              void* d_out, int out_size, void* d_ws, size_t ws_size,
                              hipStream_t stream) {
    const float* la = (const float*)d_in[0];   // [256][1024]
    const float* W  = (const float*)d_in[1];   // [1024][1024]
    float* out = (float*)d_out;                // [256][1024]

    char* ws = (char*)d_ws;
    unsigned* bar = (unsigned*)ws;                 // 256 B (poisoned 0xAA -> memset)
    float* lcs_g  = (float*)(ws + 4096);           // 4 KB
    float* psum   = (float*)(ws + 8192);           // 64 KB [16][1024]
    ushort* Ph    = (ushort*)(ws + (128 << 10));   // 2 MB
    ushort* Pl    = Ph + (size_t)N * N;            // 2 MB

    hipMemsetAsync(bar, 0, 256, stream);           // zero barrier counters
    fused<<<NBLK, 512, 0, stream>>>(la, W, out, bar, lcs_g, psum, Ph, Pl);
}

// Round 10
// 78.106 us; speedup vs baseline: 1.2556x; 1.2556x over previous
//
#include <hip/hip_runtime.h>
#include <hip/hip_bf16.h>

#define N 1024
#define BATCH 256

typedef __attribute__((ext_vector_type(4))) short short4v;
typedef __attribute__((ext_vector_type(8))) short short8;
typedef __attribute__((ext_vector_type(4))) float f32x4;

static __device__ __forceinline__ ushort bfbits(float f) {
    union { __hip_bfloat16 h; ushort u; } cv; cv.h = __float2bfloat16(f); return cv.u;
}
static __device__ __forceinline__ float bf2f(ushort u) {
    union { ushort u; __hip_bfloat16 h; } cv; cv.u = u; return __bfloat162float(cv.h);
}

#define MFMA16(a, b, c) __builtin_amdgcn_mfma_f32_16x16x32_bf16(a, b, c, 0, 0, 0)

// ---------------------------------------------------------------------------
// K1: Ph/Pl = bf16 hi/lo split of exp(W); psum[slab][j] = 16-row column sums.
// grid 256 = 64 row-slabs(16) x 4 col-groups(256).  (validated R4/R6)
// ---------------------------------------------------------------------------
__global__ __launch_bounds__(256) void k1_psplit(const float* __restrict__ W,
                                                 float* __restrict__ psum,
                                                 ushort* __restrict__ Ph,
                                                 ushort* __restrict__ Pl) {
    const int t = threadIdx.x, lane = t & 63, w = t >> 6;
    const int cg = blockIdx.x & 3, slab = blockIdx.x >> 2;
    const int c = cg * 256 + lane * 4;
    __shared__ f32x4 sm[4][64];
    f32x4 acc = {0.f, 0.f, 0.f, 0.f};
#pragma unroll
    for (int it = 0; it < 4; ++it) {
        const int row = slab * 16 + w * 4 + it;
        const f32x4 v = *(const f32x4*)(W + row * N + c);
        short4v ph, pl;
        f32x4 e;
#pragma unroll
        for (int x = 0; x < 4; ++x) {
            e[x] = __expf(v[x]);
            const ushort h = bfbits(e[x]);
            ph[x] = (short)h;
            pl[x] = (short)bfbits(e[x] - bf2f(h));
        }
        *(short4v*)(Ph + row * N + c) = ph;
        *(short4v*)(Pl + row * N + c) = pl;
        acc += e;
    }
    sm[w][lane] = acc;
    __syncthreads();
    if (t < 64)
        *(f32x4*)(psum + slab * N + c) =
            sm[0][lane] + sm[1][lane] + sm[2][lane] + sm[3][lane];
}

// ---------------------------------------------------------------------------
// K2: lcs = log(colsum) from 64 slab partials; Qh/Ql = split of exp(la-lcs).
// grid 256 = 16 m-groups(16 rows) x 16 col-groups(64 cols).  (validated R6)
// ---------------------------------------------------------------------------
__global__ __launch_bounds__(256) void k2_qsplit(const float* __restrict__ la,
                                                 const float* __restrict__ psum,
                                                 ushort* __restrict__ Qh,
                                                 ushort* __restrict__ Ql) {
    const int t = threadIdx.x;
    const int cg = blockIdx.x & 15, mg = blockIdx.x >> 4;
    const int c0 = cg * 64;
    __shared__ float smred[4][64];
    __shared__ float lcs[64];

    {
        const int col = t & 63, sg = t >> 6;
        float a = 0.f;
#pragma unroll
        for (int i = 0; i < 16; ++i)
            a += psum[(sg * 16 + i) * N + c0 + col];
        smred[sg][col] = a;
    }
    __syncthreads();
    if (t < 64)
        lcs[t] = __logf(smred[0][t] + smred[1][t] + smred[2][t] + smred[3][t]);
    __syncthreads();

    const int row = mg * 16 + (t >> 4);
    const int cc  = (t & 15) * 4;
    const f32x4 v = *(const f32x4*)(la + row * N + c0 + cc);
    short4v qh, ql;
#pragma unroll
    for (int x = 0; x < 4; ++x) {
        const float qv = __expf(v[x] - lcs[cc + x]);
        const ushort h = bfbits(qv);
        qh[x] = (short)h;
        ql[x] = (short)bfbits(qv - bf2f(h));
    }
    *(short4v*)(Qh + row * N + c0 + cc) = qh;
    *(short4v*)(Ql + row * N + c0 + cc) = ql;
}

// ---------------------------------------------------------------------------
// K3: out[m][i] = log( sum_j Q[m][j]*P[i][j] ), split-3 bf16 MFMA.
// Direct-global fragment loads (no LDS staging — LDS version is 2-3:1
// LDS-pipe-bound for split-3; fragment pattern is line-perfect: one wave =
// 16 rows x 64B contiguous per load instr).  Double-buffered GROUP pipeline:
// 4 chunks (K=128) per group, 16 loads/group in flight while the previous
// group's 12 MFMAs run.  All buffer indices compile-time (rule #20).
// 256 blocks (8 m x 32 i), 512 thr = 8 waves: 2x2 quadrants x K-split-2.
// ---------------------------------------------------------------------------
__global__ __launch_bounds__(512, 2) void k3_mm(const ushort* __restrict__ Qh,
                                                const ushort* __restrict__ Ql,
                                                const ushort* __restrict__ Ph,
                                                const ushort* __restrict__ Pl,
                                                float* __restrict__ out) {
    __shared__ f32x4 red[512];

    const int t    = threadIdx.x;
    const int lane = t & 63;
    const int wid  = t >> 6;              // 0..7
    const int wm   = (wid >> 1) & 1;
    const int wn   = wid & 1;
    const int g    = wid >> 2;            // K-half (512 each)
    const int m0   = (blockIdx.x >> 5) * 32;
    const int i0   = (blockIdx.x & 31) * 32;

    const int fr = lane & 15;             // fragment row
    const int kb = g * 512 + (lane >> 4) * 8;
    const ushort* pAh = Qh + (m0 + wm * 16 + fr) * N + kb;
    const ushort* pAl = Ql + (m0 + wm * 16 + fr) * N + kb;
    const ushort* pBh = Ph + (i0 + wn * 16 + fr) * N + kb;
    const ushort* pBl = Pl + (i0 + wn * 16 + fr) * N + kb;

    // buf[set][chunk][frag]: all indices literal after unroll -> registers
    short8 buf[2][4][4];
#pragma unroll
    for (int c = 0; c < 4; ++c) {         // prologue: group 0 (chunks 0-3)
        buf[0][c][0] = *(const short8*)(pAh + c * 32);
        buf[0][c][1] = *(const short8*)(pAl + c * 32);
        buf[0][c][2] = *(const short8*)(pBh + c * 32);
        buf[0][c][3] = *(const short8*)(pBl + c * 32);
    }

    f32x4 acc0 = {0.f, 0.f, 0.f, 0.f};
    f32x4 acc1 = {0.f, 0.f, 0.f, 0.f};

#pragma unroll
    for (int grp = 0; grp < 4; ++grp) {
        const int cur = grp & 1, nxt = cur ^ 1;
        if (grp < 3) {                    // load next group (chunks grp*4+4..7)
#pragma unroll
            for (int c = 0; c < 4; ++c) {
                const int k = (grp + 1) * 4 + c;
                buf[nxt][c][0] = *(const short8*)(pAh + k * 32);
                buf[nxt][c][1] = *(const short8*)(pAl + k * 32);
                buf[nxt][c][2] = *(const short8*)(pBh + k * 32);
                buf[nxt][c][3] = *(const short8*)(pBl + k * 32);
            }
        }
#pragma unroll
        for (int c = 0; c < 4; ++c) {     // 12 MFMAs on current group
            const short8 ah = buf[cur][c][0], al = buf[cur][c][1];
            const short8 bh = buf[cur][c][2], bl = buf[cur][c][3];
            if (c & 1) {
                acc1 = MFMA16(ah, bh, acc1);
                acc1 = MFMA16(ah, bl, acc1);
                acc1 = MFMA16(al, bh, acc1);
            } else {
                acc0 = MFMA16(ah, bh, acc0);
                acc0 = MFMA16(ah, bl, acc0);
                acc0 = MFMA16(al, bh, acc0);
            }
        }
    }

    red[wid * 64 + lane] = acc0 + acc1;
    __syncthreads();
    if (wid < 4) {                        // partner wave wid+4 = other K-half
        const f32x4 s = red[wid * 64 + lane] + red[(wid + 4) * 64 + lane];
        const int om = m0 + wm * 16 + (lane >> 4) * 4;
        const int oi = i0 + wn * 16 + fr;
#pragma unroll
        for (int r = 0; r < 4; ++r)
            out[(om + r) * N + oi] = __logf(s[r]);
    }
}

// ---------------------------------------------------------------------------
extern "C" void kernel_launch(void* const* d_in, const int* in_sizes, int n_in,
                              void* d_out, int out_size, void* d_ws, size_t ws_size,
                              hipStream_t stream) {
    const float* la = (const float*)d_in[0];   // [256][1024]
    const float* W  = (const float*)d_in[1];   // [1024][1024]
    float* out = (float*)d_out;                // [256][1024]

    char* ws = (char*)d_ws;
    float*  psum = (float*)ws;                             // 256 KB (64 slabs)
    ushort* Ph   = (ushort*)(ws + (256 << 10));            // 2 MB
    ushort* Pl   = Ph + (size_t)N * N;                     // 2 MB
    ushort* Qh   = Pl + (size_t)N * N;                     // 512 KB
    ushort* Ql   = Qh + (size_t)BATCH * N;                 // 512 KB

    k1_psplit<<<256, 256, 0, stream>>>(W, psum, Ph, Pl);
    k2_qsplit<<<256, 256, 0, stream>>>(la, psum, Qh, Ql);
    k3_mm<<<256, 512, 0, stream>>>(Qh, Ql, Ph, Pl, out);
}

// Round 11
// 68.569 us; speedup vs baseline: 1.4302x; 1.1391x over previous
//
#include <hip/hip_runtime.h>
#include <hip/hip_bf16.h>

#define N 1024
#define BATCH 256
#define LP 264   // LDS row stride (elements): 256 data + 8 pad; 132 dw = 4 mod 32 banks

typedef __attribute__((ext_vector_type(4))) short short4v;
typedef __attribute__((ext_vector_type(8))) short short8;
typedef __attribute__((ext_vector_type(4))) float f32x4;

static __device__ __forceinline__ ushort bfbits(float f) {
    union { __hip_bfloat16 h; ushort u; } cv; cv.h = __float2bfloat16(f); return cv.u;
}
static __device__ __forceinline__ float bf2f(ushort u) {
    union { ushort u; __hip_bfloat16 h; } cv; cv.u = u; return __bfloat162float(cv.h);
}

#define MFMA16(a, b, c) __builtin_amdgcn_mfma_f32_16x16x32_bf16(a, b, c, 0, 0, 0)

// ---------------------------------------------------------------------------
// K1: Ph/Pl = bf16 hi/lo split of exp(W); psum[slab][j] = 16-row column sums.
// grid 256 = 64 row-slabs(16) x 4 col-groups(256).  (measured, R4/R6/R10)
// ---------------------------------------------------------------------------
__global__ __launch_bounds__(256) void k1_psplit(const float* __restrict__ W,
                                                 float* __restrict__ psum,
                                                 ushort* __restrict__ Ph,
                                                 ushort* __restrict__ Pl) {
    const int t = threadIdx.x, lane = t & 63, w = t >> 6;
    const int cg = blockIdx.x & 3, slab = blockIdx.x >> 2;
    const int c = cg * 256 + lane * 4;
    __shared__ f32x4 sm[4][64];
    f32x4 acc = {0.f, 0.f, 0.f, 0.f};
#pragma unroll
    for (int it = 0; it < 4; ++it) {
        const int row = slab * 16 + w * 4 + it;
        const f32x4 v = *(const f32x4*)(W + row * N + c);
        short4v ph, pl;
        f32x4 e;
#pragma unroll
        for (int x = 0; x < 4; ++x) {
            e[x] = __expf(v[x]);
            const ushort h = bfbits(e[x]);
            ph[x] = (short)h;
            pl[x] = (short)bfbits(e[x] - bf2f(h));
        }
        *(short4v*)(Ph + row * N + c) = ph;
        *(short4v*)(Pl + row * N + c) = pl;
        acc += e;
    }
    sm[w][lane] = acc;
    __syncthreads();
    if (t < 64)
        *(f32x4*)(psum + slab * N + c) =
            sm[0][lane] + sm[1][lane] + sm[2][lane] + sm[3][lane];
}

// ---------------------------------------------------------------------------
// K2: lcs = log(colsum) from 64 slab partials; Qh/Ql = split of exp(la-lcs).
// grid 256 = 16 m-groups(16 rows) x 16 col-groups(64 cols).  (measured R6/R10)
// ---------------------------------------------------------------------------
__global__ __launch_bounds__(256) void k2_qsplit(const float* __restrict__ la,
                                                 const float* __restrict__ psum,
                                                 ushort* __restrict__ Qh,
                                                 ushort* __restrict__ Ql) {
    const int t = threadIdx.x;
    const int cg = blockIdx.x & 15, mg = blockIdx.x >> 4;
    const int c0 = cg * 64;
    __shared__ float smred[4][64];
    __shared__ float lcs[64];

    {
        const int col = t & 63, sg = t >> 6;
        float a = 0.f;
#pragma unroll
        for (int i = 0; i < 16; ++i)
            a += psum[(sg * 16 + i) * N + c0 + col];
        smred[sg][col] = a;
    }
    __syncthreads();
    if (t < 64)
        lcs[t] = __logf(smred[0][t] + smred[1][t] + smred[2][t] + smred[3][t]);
    __syncthreads();

    const int row = mg * 16 + (t >> 4);
    const int cc  = (t & 15) * 4;
    const f32x4 v = *(const f32x4*)(la + row * N + c0 + cc);
    short4v qh, ql;
#pragma unroll
    for (int x = 0; x < 4; ++x) {
        const float qv = __expf(v[x] - lcs[cc + x]);
        const ushort h = bfbits(qv);
        qh[x] = (short)h;
        ql[x] = (short)bfbits(qv - bf2f(h));
    }
    *(short4v*)(Qh + row * N + c0 + cc) = qh;
    *(short4v*)(Ql + row * N + c0 + cc) = ql;
}

// ---------------------------------------------------------------------------
// K3: out[m][i] = log( sum_j Q[m][j]*P[i][j] ), split-3 bf16 MFMA.
// R4's measured-best LDS-staged structure (direct-global regressed 2x runs:
// compiler won't hold a register load-pipeline) with two tweaks:
//  - B-fragment reuse: wave (wn,g) computes BOTH wm quadrants of its wn
//    column -> bPh/bPl read once per slice feed 6 MFMAs (reads/MFMA 1.33->1.0;
//    384 instead of 512 ds_read_b128 per block).
//  - BK=256: 4 iters, 8 barriers (was 8 iters / 16 barriers).
// 256 blocks (8 m x 32 i), 512 thr = 8 waves: 2 wn-columns x K-split-4.
// Row stride 264 el = 132 dw = 4 mod 32 -> stage-writes and reads <=2-way.
// ---------------------------------------------------------------------------
__global__ __launch_bounds__(512) void k3_mm(const ushort* __restrict__ Qh,
                                             const ushort* __restrict__ Ql,
                                             const ushort* __restrict__ Ph,
                                             const ushort* __restrict__ Pl,
                                             float* __restrict__ out) {
    __shared__ ushort sQh[32 * LP], sQl[32 * LP];
    __shared__ ushort sPh[32 * LP], sPl[32 * LP];

    const int t    = threadIdx.x;
    const int lane = t & 63;
    const int wid  = t >> 6;              // 0..7
    const int wn   = wid & 1;             // i-quadrant column
    const int g    = wid >> 1;            // K-split group 0..3 (64 K each/iter)
    const int m0   = (blockIdx.x >> 5) * 32;
    const int i0   = (blockIdx.x & 31) * 32;

    // staging: thread t owns row t>>4, cols (t&15)*8 and +128 (2 b128/array)
    const int srow = t >> 4;
    const int skc  = (t & 15) * 8;
    const ushort* gQh = Qh + (m0 + srow) * N + skc;
    const ushort* gQl = Ql + (m0 + srow) * N + skc;
    const ushort* gPh = Ph + (i0 + srow) * N + skc;
    const ushort* gPl = Pl + (i0 + srow) * N + skc;
    const int sd0 = srow * LP + skc;
    const int sd1 = sd0 + 128;

    // fragments: lane = row (l&15), 8 consecutive k at (l>>4)*8
    const int fr  = lane & 15;
    const int fkb = g * 64 + (lane >> 4) * 8;
    const int a0off = (fr) * LP + fkb;          // wm=0 rows 0..15
    const int a1off = (16 + fr) * LP + fkb;     // wm=1 rows 16..31
    const int boff  = (wn * 16 + fr) * LP + fkb;

    f32x4 acc0 = {0.f, 0.f, 0.f, 0.f};   // wm=0 quadrant
    f32x4 acc1 = {0.f, 0.f, 0.f, 0.f};   // wm=1 quadrant

    // register prefetch of chunk 0 (R4-verified staging pattern)
    short8 vqh0 = *(const short8*)(gQh),       vqh1 = *(const short8*)(gQh + 128);
    short8 vql0 = *(const short8*)(gQl),       vql1 = *(const short8*)(gQl + 128);
    short8 vph0 = *(const short8*)(gPh),       vph1 = *(const short8*)(gPh + 128);
    short8 vpl0 = *(const short8*)(gPl),       vpl1 = *(const short8*)(gPl + 128);

    for (int k0 = 0; k0 < N; k0 += 256) {
        __syncthreads();                       // prev iter's fragment reads done
        *(short8*)&sQh[sd0] = vqh0;  *(short8*)&sQh[sd1] = vqh1;
        *(short8*)&sQl[sd0] = vql0;  *(short8*)&sQl[sd1] = vql1;
        *(short8*)&sPh[sd0] = vph0;  *(short8*)&sPh[sd1] = vph1;
        *(short8*)&sPl[sd0] = vpl0;  *(short8*)&sPl[sd1] = vpl1;
        if (k0 + 256 < N) {                    // prefetch flies across barrier+MFMA
            vqh0 = *(const short8*)(gQh + k0 + 256);  vqh1 = *(const short8*)(gQh + k0 + 384);
            vql0 = *(const short8*)(gQl + k0 + 256);  vql1 = *(const short8*)(gQl + k0 + 384);
            vph0 = *(const short8*)(gPh + k0 + 256);  vph1 = *(const short8*)(gPh + k0 + 384);
            vpl0 = *(const short8*)(gPl + k0 + 256);  vpl1 = *(const short8*)(gPl + k0 + 384);
        }
        __syncthreads();                       // tile staged
#pragma unroll
        for (int ks = 0; ks < 2; ++ks) {       // 2 slices of K=32 per wave
            const int so = ks * 32;
            const short8 bh  = *(const short8*)&sPh[boff + so];
            const short8 bl  = *(const short8*)&sPl[boff + so];
            const short8 ah0 = *(const short8*)&sQh[a0off + so];
            const short8 al0 = *(const short8*)&sQl[a0off + so];
            const short8 ah1 = *(const short8*)&sQh[a1off + so];
            const short8 al1 = *(const short8*)&sQl[a1off + so];
            acc0 = MFMA16(ah0, bh, acc0);
            acc0 = MFMA16(ah0, bl, acc0);
            acc0 = MFMA16(al0, bh, acc0);
            acc1 = MFMA16(ah1, bh, acc1);
            acc1 = MFMA16(ah1, bl, acc1);
            acc1 = MFMA16(al1, bh, acc1);
        }
    }

    // K-split-4 reduce: red[wid][lane][wm], reuse sQh (16KB <= 16.9KB)
    __syncthreads();
    f32x4* red = (f32x4*)sQh;
    red[(wid * 64 + lane) * 2 + 0] = acc0;
    red[(wid * 64 + lane) * 2 + 1] = acc1;
    __syncthreads();
    if (wid < 4) {                        // output quadrant (wm_o, wn_o)
        const int wm_o = wid >> 1, wn_o = wid & 1;
        f32x4 s = {0.f, 0.f, 0.f, 0.f};
#pragma unroll
        for (int gg = 0; gg < 4; ++gg)
            s += red[((gg * 2 + wn_o) * 64 + lane) * 2 + wm_o];
        const int om = m0 + wm_o * 16 + (lane >> 4) * 4;
        const int oi = i0 + wn_o * 16 + fr;
#pragma unroll
        for (int r = 0; r < 4; ++r)
            out[(om + r) * N + oi] = __logf(s[r]);
    }
}

// ---------------------------------------------------------------------------
extern "C" void kernel_launch(void* const* d_in, const int* in_sizes, int n_in,
                              void* d_out, int out_size, void* d_ws, size_t ws_size,
                              hipStream_t stream) {
    const float* la = (const float*)d_in[0];   // [256][1024]
    const float* W  = (const float*)d_in[1];   // [1024][1024]
    float* out = (float*)d_out;                // [256][1024]

    char* ws = (char*)d_ws;
    float*  psum = (float*)ws;                             // 256 KB (64 slabs)
    ushort* Ph   = (ushort*)(ws + (256 << 10));            // 2 MB
    ushort* Pl   = Ph + (size_t)N * N;                     // 2 MB
    ushort* Qh   = Pl + (size_t)N * N;                     // 512 KB
    ushort* Ql   = Qh + (size_t)BATCH * N;                 // 512 KB

    k1_psplit<<<256, 256, 0, stream>>>(W, psum, Ph, Pl);
    k2_qsplit<<<256, 256, 0, stream>>>(la, psum, Qh, Ql);
    k3_mm<<<256, 512, 0, stream>>>(Qh, Ql, Ph, Pl, out);
}